// Round 1
// 179.239 us; speedup vs baseline: 1.0593x; 1.0593x over previous
//
#include <hip/hip_runtime.h>
#include <cstddef>

constexpr int Bc = 2, Sc = 2048, Hc = 16, Dc = 64, HIDc = 1024;
#define NEG_INF -10000.0f
#define LOG2E 1.44269504088896340736f

typedef _Float16 half8  __attribute__((ext_vector_type(8)));  // K=32 MFMA A/B frag
typedef _Float16 half4  __attribute__((ext_vector_type(4)));  // K=16 MFMA A/B frag
typedef float   floatx4 __attribute__((ext_vector_type(4)));  // MFMA C/D frag

// ---------------------------------------------------------------------------
// cvt_x: x fp32 [4096][1024] -> f16 same layout. 8 elements/thread.
// ---------------------------------------------------------------------------
__global__ __launch_bounds__(256) void cvt_x_kernel(const float* __restrict__ x,
                                                    _Float16* __restrict__ xh) {
    int i = (blockIdx.x * 256 + threadIdx.x) * 8;
    float4 a = *(const float4*)(x + i);
    float4 b = *(const float4*)(x + i + 4);
    half8 h;
    h[0] = (_Float16)a.x; h[1] = (_Float16)a.y; h[2] = (_Float16)a.z; h[3] = (_Float16)a.w;
    h[4] = (_Float16)b.x; h[5] = (_Float16)b.y; h[6] = (_Float16)b.z; h[7] = (_Float16)b.w;
    *(half8*)(xh + i) = h;
}

// ---------------------------------------------------------------------------
// cvt_w: W fp32 [k][n] -> Wt f16 [n][k] (transposed), per z in {q,k,v}.
// ---------------------------------------------------------------------------
__global__ __launch_bounds__(256) void cvt_w_kernel(const float* __restrict__ Wq,
                                                    const float* __restrict__ Wk,
                                                    const float* __restrict__ Wv,
                                                    _Float16* __restrict__ Wt) {
    const float* W = (blockIdx.z == 0) ? Wq : (blockIdx.z == 1) ? Wk : Wv;
    _Float16* out = Wt + (size_t)blockIdx.z * HIDc * HIDc;
    __shared__ _Float16 T[64][65];
    const int t = threadIdx.x;
    const int kb = blockIdx.x * 64, nb = blockIdx.y * 64;
    const int r = t >> 2, c4 = (t & 3) * 16;
    #pragma unroll
    for (int i = 0; i < 16; i += 4) {
        float4 a = *(const float4*)(W + (size_t)(kb + r) * HIDc + nb + c4 + i);
        T[c4 + i + 0][r] = (_Float16)a.x;
        T[c4 + i + 1][r] = (_Float16)a.y;
        T[c4 + i + 2][r] = (_Float16)a.z;
        T[c4 + i + 3][r] = (_Float16)a.w;
    }
    __syncthreads();
    const int n = t >> 2, k4 = (t & 3) * 16;
    half8 o0, o1;
    #pragma unroll
    for (int j = 0; j < 8; ++j) { o0[j] = T[n][k4 + j]; o1[j] = T[n][k4 + 8 + j]; }
    *(half8*)(out + (size_t)(nb + n) * HIDc + kb + k4)     = o0;
    *(half8*)(out + (size_t)(nb + n) * HIDc + kb + k4 + 8) = o1;
}

// ---------------------------------------------------------------------------
// proj R11: K-loop identical to R10. Changes:
//  - z==0 scale folds log2e (attn now uses exp2 directly): 0.125 * log2(e)
//  - z==2 (V^T) epilogue routed through LDS transpose: the old path issued 64
//    scalar 2B stores/lane whose lanes scattered across 4KB-strided rows.
//    C-tile -> T[n][m] (stride 136, half4 writes, 2-way max bank aliasing)
//    -> coalesced uint4 stores (4 lanes = 128B contiguous per vt row).
// ---------------------------------------------------------------------------
#define PSTR 40
__global__ __launch_bounds__(256, 2) void proj_kernel(
    const _Float16* __restrict__ xh, const _Float16* __restrict__ Wt,
    const float* __restrict__ bq, const float* __restrict__ bk, const float* __restrict__ bv,
    _Float16* __restrict__ qw, _Float16* __restrict__ kw, _Float16* __restrict__ vt)
{
    const int z = blockIdx.z;
    const _Float16* Wz = Wt + (size_t)z * HIDc * HIDc;
    const float* bias = (z == 0) ? bq : (z == 1) ? bk : bv;

    // SM[0..1] = A double-buffer, SM[2..3] = B double-buffer (flat so the
    // z==2 epilogue can reuse the whole 40KB as a 128x136 f16 transpose tile)
    __shared__ __align__(16) _Float16 SM[4][128 * PSTR];

    const int t = threadIdx.x;
    const int lane = t & 63, w = t >> 6;
    const int quad = lane >> 4, l16 = lane & 15;
    const int m0 = blockIdx.y * 128, n0 = blockIdx.x * 128;
    const int wm = (w >> 1) * 64, wn = (w & 1) * 64;
    const int sr = t >> 1, sh = (t & 1) * 16;

    floatx4 acc[4][4];
    #pragma unroll
    for (int mb = 0; mb < 4; ++mb)
        #pragma unroll
        for (int nb = 0; nb < 4; ++nb) acc[mb][nb] = floatx4{0.f, 0.f, 0.f, 0.f};

    // ---- preload k-tile 0 into buffer 0
    {
        const _Float16* ap = xh + (size_t)(m0 + sr) * HIDc + sh;
        const _Float16* bp = Wz + (size_t)(n0 + sr) * HIDc + sh;
        *(uint4*)(SM[0] + sr * PSTR + sh)     = *(const uint4*)(ap);
        *(uint4*)(SM[0] + sr * PSTR + sh + 8) = *(const uint4*)(ap + 8);
        *(uint4*)(SM[2] + sr * PSTR + sh)     = *(const uint4*)(bp);
        *(uint4*)(SM[2] + sr * PSTR + sh + 8) = *(const uint4*)(bp + 8);
    }
    __syncthreads();

    #pragma unroll 2
    for (int it = 0; it < HIDc / 32; ++it) {
        const int cur = it & 1;
        // ---- issue global loads for tile it+1 (dummy reload of 0 on last)
        const int kn = (it + 1 < HIDc / 32) ? (it + 1) * 32 : 0;
        const _Float16* ap = xh + (size_t)(m0 + sr) * HIDc + kn + sh;
        const _Float16* bp = Wz + (size_t)(n0 + sr) * HIDc + kn + sh;
        uint4 a0 = *(const uint4*)(ap);
        uint4 a1 = *(const uint4*)(ap + 8);
        uint4 b0 = *(const uint4*)(bp);
        uint4 b1 = *(const uint4*)(bp + 8);

        // ---- frags from buf[cur] + MFMA
        half8 af[4], bf[4];
        #pragma unroll
        for (int mb = 0; mb < 4; ++mb)
            af[mb] = *(const half8*)(SM[cur] + (wm + mb * 16 + l16) * PSTR + quad * 8);
        #pragma unroll
        for (int nb = 0; nb < 4; ++nb)
            bf[nb] = *(const half8*)(SM[2 + cur] + (wn + nb * 16 + l16) * PSTR + quad * 8);
        #pragma unroll
        for (int mb = 0; mb < 4; ++mb)
            #pragma unroll
            for (int nb = 0; nb < 4; ++nb)
                acc[mb][nb] = __builtin_amdgcn_mfma_f32_16x16x32_f16(
                    af[mb], bf[nb], acc[mb][nb], 0, 0, 0);

        // ---- stage tile it+1 into buf[cur^1] (readers finished last iter)
        *(uint4*)(SM[cur ^ 1] + sr * PSTR + sh)           = a0;
        *(uint4*)(SM[cur ^ 1] + sr * PSTR + sh + 8)       = a1;
        *(uint4*)(SM[2 + (cur ^ 1)] + sr * PSTR + sh)     = b0;
        *(uint4*)(SM[2 + (cur ^ 1)] + sr * PSTR + sh + 8) = b1;
        __syncthreads();
    }

    // epilogue: C/D mapping col=lane&15, row=quad*4+reg (m89/m91-verified)
    if (z == 2) {
        // ---- V^T via LDS transpose: T[n][m], stride 136 halves
        _Float16* T = &SM[0][0];
        #pragma unroll
        for (int nb = 0; nb < 4; ++nb) {
            const int n = wn + nb * 16 + l16;
            const float bi = bias[n0 + n];
            #pragma unroll
            for (int mb = 0; mb < 4; ++mb) {
                half4 h4;
                #pragma unroll
                for (int r = 0; r < 4; ++r) h4[r] = (_Float16)(acc[mb][nb][r] + bi);
                *(half4*)(T + n * 136 + wm + mb * 16 + quad * 4) = h4;
            }
        }
        __syncthreads();
        const int bI0 = m0 >> 11, m0s = m0 & (Sc - 1);
        #pragma unroll
        for (int p = 0; p < 2; ++p) {
            const int n = p * 64 + (t >> 2);
            const int N = n0 + n, hh = N >> 6, d = N & 63;
            _Float16* vrow = vt + (((size_t)(bI0 * Hc + hh)) * Dc + d) * Sc + m0s;
            #pragma unroll
            for (int j = 0; j < 4; ++j) {
                const int c = (t & 3) * 32 + j * 8;
                *(uint4*)(vrow + c) = *(const uint4*)(T + n * 136 + c);
            }
        }
        return;
    }
    #pragma unroll
    for (int nb = 0; nb < 4; ++nb) {
        const int N = n0 + wn + nb * 16 + l16;
        const float bi = bias[N];
        const int h = N >> 6, d = N & 63;
        #pragma unroll
        for (int mb = 0; mb < 4; ++mb) {
            #pragma unroll
            for (int r = 0; r < 4; ++r) {
                const int M = m0 + wm + mb * 16 + quad * 4 + r;
                const int bI = M >> 11, s = M & (Sc - 1);
                const float v = acc[mb][nb][r] + bi;
                if (z == 0)
                    qw[(((size_t)(bI * Hc + h)) * Sc + s) * Dc + d] =
                        (_Float16)(v * (0.125f * LOG2E));
                else
                    kw[(((size_t)(bI * Hc + h)) * Sc + s) * Dc + d] = (_Float16)v;
            }
        }
    }
}

// ---------------------------------------------------------------------------
// attn R11: same zero-shuffle transposed-scores structure as R9/R10, but:
//  - mask adder (pre-scaled by log2e) is the QK MFMA C-initializer: the C
//    layout row=key=quad*4+r matches the float4 adder load exactly (-32 add)
//  - p = exp2(st) directly (log2e folded into q-scale + adder) (-32 mul)
//  - softmax denominator via ones-column PV MFMA: osum = mfma(pa, 1, osum)
//    lands the full row-sum at the (quad,r) lane the epilogue needs
//    (-32 add, no end shuffles, numerator/denominator rounding consistent)
//  - V stored in LDS with permuted key columns (key nb*16+q*4+r -> col
//    q*16+nb*4+r): the 16 4-way-conflicted b64 V reads become 8 conflict-
//    free b128 reads.
// ---------------------------------------------------------------------------
__global__ __launch_bounds__(256, 2) void attn_kernel(
    const _Float16* __restrict__ qw, const _Float16* __restrict__ kw,
    const _Float16* __restrict__ vt, const int* __restrict__ mask,
    float* __restrict__ out)
{
    __shared__ __align__(16) float adder[Sc];           // 8 KB (pre-scaled log2e)
    __shared__ __align__(16) _Float16 Ks[2][64][72];    // 18 KB  [key][d]
    __shared__ __align__(16) _Float16 Vs[2][64][72];    // 18 KB  [d][key-permuted]

    const int t = threadIdx.x;
    const int lane = t & 63, w = t >> 6;
    const int quad = lane >> 4, l16 = lane & 15;
    const int bh = blockIdx.y;
    const int bI = bh >> 4, h = bh & 15;

    const _Float16* Qp = qw + (size_t)bh * Sc * Dc;
    const _Float16* Kp = kw + (size_t)bh * Sc * Dc;
    const _Float16* Vp = vt + (size_t)bh * Dc * Sc;

    const int srow = t >> 3;            // 0..31
    const int scol = (t & 7) * 8;       // elem offset, 16 B per thread
    const int m7 = t & 7;
    const int vc0 = 32 * (m7 & 1) + 4 * (m7 >> 1);   // permuted V col base

    {   // mask -> additive adder in LDS, pre-scaled by log2e
        const int4* mp = (const int4*)(mask + bI * Sc);
        #pragma unroll
        for (int i = 0; i < 2; ++i) {
            int4 m4 = mp[t * 2 + i];
            int base = (t * 2 + i) * 4;
            adder[base + 0] = (1.0f - (float)m4.x) * (NEG_INF * LOG2E);
            adder[base + 1] = (1.0f - (float)m4.y) * (NEG_INF * LOG2E);
            adder[base + 2] = (1.0f - (float)m4.z) * (NEG_INF * LOG2E);
            adder[base + 3] = (1.0f - (float)m4.w) * (NEG_INF * LOG2E);
        }
    }
    // preload tile 0 into buffer 0 (V columns permuted)
    #pragma unroll
    for (int hf = 0; hf < 2; ++hf) {
        const int row = srow + 32 * hf;
        uint4 kv = *(const uint4*)(Kp + (size_t)row * Dc + scol);
        uint4 vv = *(const uint4*)(Vp + (size_t)row * Sc + scol);
        *(uint4*)(&Ks[0][row][scol]) = kv;
        *(uint2*)(&Vs[0][row][vc0])      = make_uint2(vv.x, vv.y);
        *(uint2*)(&Vs[0][row][vc0 + 16]) = make_uint2(vv.z, vv.w);
    }

    const int qrow = blockIdx.x * 128 + w * 32;
    half8 aq[2][2];
    #pragma unroll
    for (int s = 0; s < 2; ++s)
        #pragma unroll
        for (int hh = 0; hh < 2; ++hh)
            aq[s][hh] = *(const half8*)(Qp + (size_t)(qrow + 16 * s + l16) * Dc
                                        + hh * 32 + quad * 8);

    floatx4 o[2][4], osum[2];
    #pragma unroll
    for (int s = 0; s < 2; ++s) {
        osum[s] = floatx4{0.f, 0.f, 0.f, 0.f};
        #pragma unroll
        for (int db = 0; db < 4; ++db) o[s][db] = floatx4{0.f, 0.f, 0.f, 0.f};
    }
    const half4 ones4 = {(_Float16)1.f, (_Float16)1.f, (_Float16)1.f, (_Float16)1.f};

    __syncthreads();   // adder + tile 0 visible

    #pragma unroll 2
    for (int it = 0; it < Sc / 64; ++it) {
        const int cur = it & 1;
        const int kt = it * 64;
        const int ktn = (it + 1 < Sc / 64) ? kt + 64 : 0;
        uint4 kstg[2], vstg[2];
        #pragma unroll
        for (int hf = 0; hf < 2; ++hf) {
            const int row = srow + 32 * hf;
            kstg[hf] = *(const uint4*)(Kp + (size_t)(ktn + row) * Dc + scol);
            vstg[hf] = *(const uint4*)(Vp + (size_t)row * Sc + ktn + scol);
        }

        half8 kb[4][2];   // A[m=key=l16][k=d=quad*8+j]
        #pragma unroll
        for (int nb = 0; nb < 4; ++nb)
            #pragma unroll
            for (int hh = 0; hh < 2; ++hh)
                kb[nb][hh] = *(const half8*)(&Ks[cur][nb * 16 + l16][hh * 32 + quad * 8]);

        half4 vb[4][4];   // B[n=d=l16][k=key=quad*4+i], from permuted b128s
        #pragma unroll
        for (int db = 0; db < 4; ++db)
            #pragma unroll
            for (int hf2 = 0; hf2 < 2; ++hf2) {
                const half8 v8 = *(const half8*)(&Vs[cur][db * 16 + l16][quad * 16 + hf2 * 8]);
                vb[hf2 * 2 + 0][db] = __builtin_shufflevector(v8, v8, 0, 1, 2, 3);
                vb[hf2 * 2 + 1][db] = __builtin_shufflevector(v8, v8, 4, 5, 6, 7);
            }

        // QK^T with adder as C-init
        floatx4 st[2][4];
        __builtin_amdgcn_s_setprio(1);
        #pragma unroll
        for (int nb = 0; nb < 4; ++nb) {
            const floatx4 adv = *(const floatx4*)(&adder[kt + nb * 16 + quad * 4]);
            #pragma unroll
            for (int s = 0; s < 2; ++s) {
                floatx4 x0 = __builtin_amdgcn_mfma_f32_16x16x32_f16(kb[nb][0], aq[s][0], adv, 0, 0, 0);
                st[s][nb]  = __builtin_amdgcn_mfma_f32_16x16x32_f16(kb[nb][1], aq[s][1], x0, 0, 0, 0);
            }
        }
        __builtin_amdgcn_s_setprio(0);

        // softmax numerators: p = exp2(st)
        half4 pa[2][4];
        #pragma unroll
        for (int s = 0; s < 2; ++s)
            #pragma unroll
            for (int nb = 0; nb < 4; ++nb)
                #pragma unroll
                for (int r = 0; r < 4; ++r)
                    pa[s][nb][r] = (_Float16)__builtin_amdgcn_exp2f(st[s][nb][r]);

        // PV + row-sum via ones-MFMA
        __builtin_amdgcn_s_setprio(1);
        #pragma unroll
        for (int s = 0; s < 2; ++s)
            #pragma unroll
            for (int nb = 0; nb < 4; ++nb) {
                osum[s] = __builtin_amdgcn_mfma_f32_16x16x16f16(pa[s][nb], ones4, osum[s], 0, 0, 0);
                #pragma unroll
                for (int db = 0; db < 4; ++db)
                    o[s][db] = __builtin_amdgcn_mfma_f32_16x16x16f16(
                        pa[s][nb], vb[nb][db], o[s][db], 0, 0, 0);
            }
        __builtin_amdgcn_s_setprio(0);

        #pragma unroll
        for (int hf = 0; hf < 2; ++hf) {
            const int row = srow + 32 * hf;
            *(uint4*)(&Ks[cur ^ 1][row][scol]) = kstg[hf];
            const uint4 vv = vstg[hf];
            *(uint2*)(&Vs[cur ^ 1][row][vc0])      = make_uint2(vv.x, vv.y);
            *(uint2*)(&Vs[cur ^ 1][row][vc0 + 16]) = make_uint2(vv.z, vv.w);
        }
        __syncthreads();
    }

    // epilogue: osum[s][r] already holds the full row-sum for q=quad*4+r
    float* op = out + (size_t)bI * Sc * HIDc + h * Dc;
    #pragma unroll
    for (int s = 0; s < 2; ++s)
        #pragma unroll
        for (int r = 0; r < 4; ++r) {
            const float inv = __builtin_amdgcn_rcpf(osum[s][r]);
            const int q = qrow + 16 * s + quad * 4 + r;
            #pragma unroll
            for (int db = 0; db < 4; ++db)
                op[(size_t)q * HIDc + db * 16 + l16] = o[s][db][r] * inv;
        }
}

// ---------------------------------------------------------------------------
extern "C" void kernel_launch(void* const* d_in, const int* in_sizes, int n_in,
                              void* d_out, int out_size, void* d_ws, size_t ws_size,
                              hipStream_t stream) {
    const float* x    = (const float*)d_in[0];
    const int*   mask = (const int*)  d_in[1];
    const float* Wq   = (const float*)d_in[2];
    const float* bq   = (const float*)d_in[3];
    const float* Wk   = (const float*)d_in[4];
    const float* bk   = (const float*)d_in[5];
    const float* Wv   = (const float*)d_in[6];
    const float* bv   = (const float*)d_in[7];
    float* out = (float*)d_out;

    // workspace (f16): xh 8MB | Wt 6MB | qw 8MB | kw 8MB | vt 8MB = 38MB
    char* ws = (char*)d_ws;
    _Float16* xh = (_Float16*)(ws);
    _Float16* Wt = (_Float16*)(ws + (size_t)8  * 1024 * 1024);
    _Float16* qw = (_Float16*)(ws + (size_t)14 * 1024 * 1024);
    _Float16* kw = (_Float16*)(ws + (size_t)22 * 1024 * 1024);
    _Float16* vt = (_Float16*)(ws + (size_t)30 * 1024 * 1024);

    cvt_x_kernel<<<(Bc * Sc * HIDc) / (256 * 8), 256, 0, stream>>>(x, xh);
    cvt_w_kernel<<<dim3(HIDc / 64, HIDc / 64, 3), 256, 0, stream>>>(Wq, Wk, Wv, Wt);
    proj_kernel<<<dim3(HIDc / 128, (Bc * Sc) / 128, 3), 256, 0, stream>>>(
        xh, Wt, bq, bk, bv, qw, kw, vt);
    attn_kernel<<<dim3(Sc / 128, Bc * Hc), 256, 0, stream>>>(qw, kw, vt, mask, out);
}

// Round 2
// 168.514 us; speedup vs baseline: 1.1268x; 1.0636x over previous
//
#include <hip/hip_runtime.h>
#include <cstddef>

constexpr int Bc = 2, Sc = 2048, Hc = 16, Dc = 64, HIDc = 1024;
#define NEG_INF -10000.0f
#define LOG2E 1.44269504088896340736f

typedef _Float16 half8  __attribute__((ext_vector_type(8)));  // K=32 MFMA A/B frag
typedef _Float16 half4  __attribute__((ext_vector_type(4)));  // K=16 MFMA A/B frag
typedef float   floatx4 __attribute__((ext_vector_type(4)));  // MFMA C/D frag

// direct HBM -> LDS, 16B per lane, lane i lands at ldsbase + i*16
__device__ __forceinline__ void gload_lds16(const void* g, void* l) {
    __builtin_amdgcn_global_load_lds(
        (const __attribute__((address_space(1))) unsigned int*)g,
        (__attribute__((address_space(3))) unsigned int*)l, 16, 0, 0);
}

// ---------------------------------------------------------------------------
// cvt_x: x fp32 [4096][1024] -> f16 same layout. 8 elements/thread.
// ---------------------------------------------------------------------------
__global__ __launch_bounds__(256) void cvt_x_kernel(const float* __restrict__ x,
                                                    _Float16* __restrict__ xh) {
    int i = (blockIdx.x * 256 + threadIdx.x) * 8;
    float4 a = *(const float4*)(x + i);
    float4 b = *(const float4*)(x + i + 4);
    half8 h;
    h[0] = (_Float16)a.x; h[1] = (_Float16)a.y; h[2] = (_Float16)a.z; h[3] = (_Float16)a.w;
    h[4] = (_Float16)b.x; h[5] = (_Float16)b.y; h[6] = (_Float16)b.z; h[7] = (_Float16)b.w;
    *(half8*)(xh + i) = h;
}

// ---------------------------------------------------------------------------
// cvt_w: W fp32 [k][n] -> Wt f16 [n][k] (transposed), per z in {q,k,v}.
// ---------------------------------------------------------------------------
__global__ __launch_bounds__(256) void cvt_w_kernel(const float* __restrict__ Wq,
                                                    const float* __restrict__ Wk,
                                                    const float* __restrict__ Wv,
                                                    _Float16* __restrict__ Wt) {
    const float* W = (blockIdx.z == 0) ? Wq : (blockIdx.z == 1) ? Wk : Wv;
    _Float16* out = Wt + (size_t)blockIdx.z * HIDc * HIDc;
    __shared__ _Float16 T[64][65];
    const int t = threadIdx.x;
    const int kb = blockIdx.x * 64, nb = blockIdx.y * 64;
    const int r = t >> 2, c4 = (t & 3) * 16;
    #pragma unroll
    for (int i = 0; i < 16; i += 4) {
        float4 a = *(const float4*)(W + (size_t)(kb + r) * HIDc + nb + c4 + i);
        T[c4 + i + 0][r] = (_Float16)a.x;
        T[c4 + i + 1][r] = (_Float16)a.y;
        T[c4 + i + 2][r] = (_Float16)a.z;
        T[c4 + i + 3][r] = (_Float16)a.w;
    }
    __syncthreads();
    const int n = t >> 2, k4 = (t & 3) * 16;
    half8 o0, o1;
    #pragma unroll
    for (int j = 0; j < 8; ++j) { o0[j] = T[n][k4 + j]; o1[j] = T[n][k4 + 8 + j]; }
    *(half8*)(out + (size_t)(nb + n) * HIDc + kb + k4)     = o0;
    *(half8*)(out + (size_t)(nb + n) * HIDc + kb + k4 + 8) = o1;
}

// ---------------------------------------------------------------------------
// proj R12: m97-structure port. 128x128 tile, BK=32, global_load_lds(16B)
// direct HBM->LDS staging (no reg round-trip, no ds_write), one barrier per
// K-step, double-buffered 32KB LDS -> 3 blocks/CU (grid 768 = 3x256, no
// tail). LDS rows are 64B so frag reads would be 8-way bank-conflicted;
// fixed by XOR-swizzling the 16B slot with (row>>1)&3 — applied on the
// GLOBAL source address (gload_lds dest must stay linear) and on the
// ds_read address (rule 21: both-sides-or-neither).
// ---------------------------------------------------------------------------
__global__ __launch_bounds__(256, 3) void proj_kernel(
    const _Float16* __restrict__ xh, const _Float16* __restrict__ Wt,
    const float* __restrict__ bq, const float* __restrict__ bk, const float* __restrict__ bv,
    _Float16* __restrict__ qw, _Float16* __restrict__ kw, _Float16* __restrict__ vt)
{
    const int z = blockIdx.z;
    const _Float16* Wz = Wt + (size_t)z * HIDc * HIDc;
    const float* bias = (z == 0) ? bq : (z == 1) ? bk : bv;

    // [buf][A=0/B=1][128 rows x 32 halves] = 32 KB total
    __shared__ __align__(16) _Float16 SM[2][2][128 * 32];

    const int t = threadIdx.x;
    const int lane = t & 63, w = t >> 6;
    const int quad = lane >> 4, l16 = lane & 15;
    const int m0 = blockIdx.y * 128, n0 = blockIdx.x * 128;
    const int wm = (w >> 1) * 64, wn = (w & 1) * 64;

    // staging geometry: one gload_lds = 64 lanes x 16B = 16 rows x 64B
    const int srl = lane >> 2;                       // row in 16-row chunk
    const int ssl = (lane & 3) ^ ((lane >> 3) & 3);  // pre-swizzled src slot

    floatx4 acc[4][4];
    #pragma unroll
    for (int mb = 0; mb < 4; ++mb)
        #pragma unroll
        for (int nb = 0; nb < 4; ++nb) acc[mb][nb] = floatx4{0.f, 0.f, 0.f, 0.f};

    auto stage = [&](int buf, int kt) {   // kt in halves
        #pragma unroll
        for (int j = 0; j < 2; ++j) {
            const int rb = (w + 4 * j) * 16;   // wave-uniform row base
            gload_lds16(xh + (size_t)(m0 + rb + srl) * HIDc + kt + ssl * 8,
                        &SM[buf][0][rb * 32]);
            gload_lds16(Wz + (size_t)(n0 + rb + srl) * HIDc + kt + ssl * 8,
                        &SM[buf][1][rb * 32]);
        }
    };

    stage(0, 0);
    __syncthreads();   // vmcnt(0) drained by compiler before s_barrier

    // swizzled read slot: want global slot=quad, stored at quad^((row>>1)&3)
    const int sA = (quad ^ ((l16 >> 1) & 3)) * 8;

    #pragma unroll 2
    for (int it = 0; it < HIDc / 32; ++it) {
        const int cur = it & 1;
        const int kn = (it + 1 < HIDc / 32) ? (it + 1) * 32 : 0;
        stage(cur ^ 1, kn);   // in flight across the compute, drained at barrier

        half8 af[4], bf[4];
        #pragma unroll
        for (int mb = 0; mb < 4; ++mb)
            af[mb] = *(const half8*)(&SM[cur][0][(wm + mb * 16 + l16) * 32 + sA]);
        #pragma unroll
        for (int nb = 0; nb < 4; ++nb)
            bf[nb] = *(const half8*)(&SM[cur][1][(wn + nb * 16 + l16) * 32 + sA]);
        #pragma unroll
        for (int mb = 0; mb < 4; ++mb)
            #pragma unroll
            for (int nb = 0; nb < 4; ++nb)
                acc[mb][nb] = __builtin_amdgcn_mfma_f32_16x16x32_f16(
                    af[mb], bf[nb], acc[mb][nb], 0, 0, 0);
        __syncthreads();
    }

    // epilogue: C/D mapping col=lane&15, row=quad*4+reg (m89/m91-verified)
    if (z == 2) {
        // V^T via LDS transpose in two 64-row passes (fits 32KB): waves with
        // w&1==p own n-range [p*64, p*64+64); then all threads store
        // coalesced uint4 rows (4 lanes = 128B contiguous per vt row).
        _Float16* T = (_Float16*)SM;     // 64 x 136 halves = 17.4 KB
        const int bI0 = m0 >> 11, m0s = m0 & (Sc - 1);
        #pragma unroll
        for (int p = 0; p < 2; ++p) {
            __syncthreads();
            if ((w & 1) == p) {
                #pragma unroll
                for (int nb = 0; nb < 4; ++nb) {
                    const int n = nb * 16 + l16;     // 0..63 within pass
                    const float bi = bias[n0 + p * 64 + n];
                    #pragma unroll
                    for (int mb = 0; mb < 4; ++mb) {
                        half4 h4;
                        #pragma unroll
                        for (int r = 0; r < 4; ++r)
                            h4[r] = (_Float16)(acc[mb][nb][r] + bi);
                        *(half4*)(T + n * 136 + wm + mb * 16 + quad * 4) = h4;
                    }
                }
            }
            __syncthreads();
            const int n = t >> 2;                    // 0..63
            const int N = n0 + p * 64 + n, hh = N >> 6, d = N & 63;
            _Float16* vrow = vt + (((size_t)(bI0 * Hc + hh)) * Dc + d) * Sc + m0s;
            #pragma unroll
            for (int j = 0; j < 4; ++j) {
                const int c = (t & 3) * 32 + j * 8;
                *(uint4*)(vrow + c) = *(const uint4*)(T + n * 136 + c);
            }
        }
        return;
    }
    #pragma unroll
    for (int nb = 0; nb < 4; ++nb) {
        const int N = n0 + wn + nb * 16 + l16;
        const float bi = bias[N];
        const int h = N >> 6, d = N & 63;
        #pragma unroll
        for (int mb = 0; mb < 4; ++mb) {
            #pragma unroll
            for (int r = 0; r < 4; ++r) {
                const int M = m0 + wm + mb * 16 + quad * 4 + r;
                const int bI = M >> 11, s = M & (Sc - 1);
                const float v = acc[mb][nb][r] + bi;
                if (z == 0)
                    qw[(((size_t)(bI * Hc + h)) * Sc + s) * Dc + d] =
                        (_Float16)(v * (0.125f * LOG2E));
                else
                    kw[(((size_t)(bI * Hc + h)) * Sc + s) * Dc + d] = (_Float16)v;
            }
        }
    }
}

// ---------------------------------------------------------------------------
// attn R12: byte-identical to R11 (57.0 us, passing).
// ---------------------------------------------------------------------------
__global__ __launch_bounds__(256, 2) void attn_kernel(
    const _Float16* __restrict__ qw, const _Float16* __restrict__ kw,
    const _Float16* __restrict__ vt, const int* __restrict__ mask,
    float* __restrict__ out)
{
    __shared__ __align__(16) float adder[Sc];           // 8 KB (pre-scaled log2e)
    __shared__ __align__(16) _Float16 Ks[2][64][72];    // 18 KB  [key][d]
    __shared__ __align__(16) _Float16 Vs[2][64][72];    // 18 KB  [d][key-permuted]

    const int t = threadIdx.x;
    const int lane = t & 63, w = t >> 6;
    const int quad = lane >> 4, l16 = lane & 15;
    const int bh = blockIdx.y;
    const int bI = bh >> 4, h = bh & 15;

    const _Float16* Qp = qw + (size_t)bh * Sc * Dc;
    const _Float16* Kp = kw + (size_t)bh * Sc * Dc;
    const _Float16* Vp = vt + (size_t)bh * Dc * Sc;

    const int srow = t >> 3;            // 0..31
    const int scol = (t & 7) * 8;       // elem offset, 16 B per thread
    const int m7 = t & 7;
    const int vc0 = 32 * (m7 & 1) + 4 * (m7 >> 1);   // permuted V col base

    {   // mask -> additive adder in LDS, pre-scaled by log2e
        const int4* mp = (const int4*)(mask + bI * Sc);
        #pragma unroll
        for (int i = 0; i < 2; ++i) {
            int4 m4 = mp[t * 2 + i];
            int base = (t * 2 + i) * 4;
            adder[base + 0] = (1.0f - (float)m4.x) * (NEG_INF * LOG2E);
            adder[base + 1] = (1.0f - (float)m4.y) * (NEG_INF * LOG2E);
            adder[base + 2] = (1.0f - (float)m4.z) * (NEG_INF * LOG2E);
            adder[base + 3] = (1.0f - (float)m4.w) * (NEG_INF * LOG2E);
        }
    }
    // preload tile 0 into buffer 0 (V columns permuted)
    #pragma unroll
    for (int hf = 0; hf < 2; ++hf) {
        const int row = srow + 32 * hf;
        uint4 kv = *(const uint4*)(Kp + (size_t)row * Dc + scol);
        uint4 vv = *(const uint4*)(Vp + (size_t)row * Sc + scol);
        *(uint4*)(&Ks[0][row][scol]) = kv;
        *(uint2*)(&Vs[0][row][vc0])      = make_uint2(vv.x, vv.y);
        *(uint2*)(&Vs[0][row][vc0 + 16]) = make_uint2(vv.z, vv.w);
    }

    const int qrow = blockIdx.x * 128 + w * 32;
    half8 aq[2][2];
    #pragma unroll
    for (int s = 0; s < 2; ++s)
        #pragma unroll
        for (int hh = 0; hh < 2; ++hh)
            aq[s][hh] = *(const half8*)(Qp + (size_t)(qrow + 16 * s + l16) * Dc
                                        + hh * 32 + quad * 8);

    floatx4 o[2][4], osum[2];
    #pragma unroll
    for (int s = 0; s < 2; ++s) {
        osum[s] = floatx4{0.f, 0.f, 0.f, 0.f};
        #pragma unroll
        for (int db = 0; db < 4; ++db) o[s][db] = floatx4{0.f, 0.f, 0.f, 0.f};
    }
    const half4 ones4 = {(_Float16)1.f, (_Float16)1.f, (_Float16)1.f, (_Float16)1.f};

    __syncthreads();   // adder + tile 0 visible

    #pragma unroll 2
    for (int it = 0; it < Sc / 64; ++it) {
        const int cur = it & 1;
        const int kt = it * 64;
        const int ktn = (it + 1 < Sc / 64) ? kt + 64 : 0;
        uint4 kstg[2], vstg[2];
        #pragma unroll
        for (int hf = 0; hf < 2; ++hf) {
            const int row = srow + 32 * hf;
            kstg[hf] = *(const uint4*)(Kp + (size_t)(ktn + row) * Dc + scol);
            vstg[hf] = *(const uint4*)(Vp + (size_t)row * Sc + ktn + scol);
        }

        half8 kb[4][2];   // A[m=key=l16][k=d=quad*8+j]
        #pragma unroll
        for (int nb = 0; nb < 4; ++nb)
            #pragma unroll
            for (int hh = 0; hh < 2; ++hh)
                kb[nb][hh] = *(const half8*)(&Ks[cur][nb * 16 + l16][hh * 32 + quad * 8]);

        half4 vb[4][4];   // B[n=d=l16][k=key=quad*4+i], from permuted b128s
        #pragma unroll
        for (int db = 0; db < 4; ++db)
            #pragma unroll
            for (int hf2 = 0; hf2 < 2; ++hf2) {
                const half8 v8 = *(const half8*)(&Vs[cur][db * 16 + l16][quad * 16 + hf2 * 8]);
                vb[hf2 * 2 + 0][db] = __builtin_shufflevector(v8, v8, 0, 1, 2, 3);
                vb[hf2 * 2 + 1][db] = __builtin_shufflevector(v8, v8, 4, 5, 6, 7);
            }

        // QK^T with adder as C-init
        floatx4 st[2][4];
        __builtin_amdgcn_s_setprio(1);
        #pragma unroll
        for (int nb = 0; nb < 4; ++nb) {
            const floatx4 adv = *(const floatx4*)(&adder[kt + nb * 16 + quad * 4]);
            #pragma unroll
            for (int s = 0; s < 2; ++s) {
                floatx4 x0 = __builtin_amdgcn_mfma_f32_16x16x32_f16(kb[nb][0], aq[s][0], adv, 0, 0, 0);
                st[s][nb]  = __builtin_amdgcn_mfma_f32_16x16x32_f16(kb[nb][1], aq[s][1], x0, 0, 0, 0);
            }
        }
        __builtin_amdgcn_s_setprio(0);

        // softmax numerators: p = exp2(st)
        half4 pa[2][4];
        #pragma unroll
        for (int s = 0; s < 2; ++s)
            #pragma unroll
            for (int nb = 0; nb < 4; ++nb)
                #pragma unroll
                for (int r = 0; r < 4; ++r)
                    pa[s][nb][r] = (_Float16)__builtin_amdgcn_exp2f(st[s][nb][r]);

        // PV + row-sum via ones-MFMA
        __builtin_amdgcn_s_setprio(1);
        #pragma unroll
        for (int s = 0; s < 2; ++s)
            #pragma unroll
            for (int nb = 0; nb < 4; ++nb) {
                osum[s] = __builtin_amdgcn_mfma_f32_16x16x16f16(pa[s][nb], ones4, osum[s], 0, 0, 0);
                #pragma unroll
                for (int db = 0; db < 4; ++db)
                    o[s][db] = __builtin_amdgcn_mfma_f32_16x16x16f16(
                        pa[s][nb], vb[nb][db], o[s][db], 0, 0, 0);
            }
        __builtin_amdgcn_s_setprio(0);

        #pragma unroll
        for (int hf = 0; hf < 2; ++hf) {
            const int row = srow + 32 * hf;
            *(uint4*)(&Ks[cur ^ 1][row][scol]) = kstg[hf];
            const uint4 vv = vstg[hf];
            *(uint2*)(&Vs[cur ^ 1][row][vc0])      = make_uint2(vv.x, vv.y);
            *(uint2*)(&Vs[cur ^ 1][row][vc0 + 16]) = make_uint2(vv.z, vv.w);
        }
        __syncthreads();
    }

    // epilogue: osum[s][r] already holds the full row-sum for q=quad*4+r
    float* op = out + (size_t)bI * Sc * HIDc + h * Dc;
    #pragma unroll
    for (int s = 0; s < 2; ++s)
        #pragma unroll
        for (int r = 0; r < 4; ++r) {
            const float inv = __builtin_amdgcn_rcpf(osum[s][r]);
            const int q = qrow + 16 * s + quad * 4 + r;
            #pragma unroll
            for (int db = 0; db < 4; ++db)
                op[(size_t)q * HIDc + db * 16 + l16] = o[s][db][r] * inv;
        }
}

// ---------------------------------------------------------------------------
extern "C" void kernel_launch(void* const* d_in, const int* in_sizes, int n_in,
                              void* d_out, int out_size, void* d_ws, size_t ws_size,
                              hipStream_t stream) {
    const float* x    = (const float*)d_in[0];
    const int*   mask = (const int*)  d_in[1];
    const float* Wq   = (const float*)d_in[2];
    const float* bq   = (const float*)d_in[3];
    const float* Wk   = (const float*)d_in[4];
    const float* bk   = (const float*)d_in[5];
    const float* Wv   = (const float*)d_in[6];
    const float* bv   = (const float*)d_in[7];
    float* out = (float*)d_out;

    // workspace (f16): xh 8MB | Wt 6MB | qw 8MB | kw 8MB | vt 8MB = 38MB
    char* ws = (char*)d_ws;
    _Float16* xh = (_Float16*)(ws);
    _Float16* Wt = (_Float16*)(ws + (size_t)8  * 1024 * 1024);
    _Float16* qw = (_Float16*)(ws + (size_t)14 * 1024 * 1024);
    _Float16* kw = (_Float16*)(ws + (size_t)22 * 1024 * 1024);
    _Float16* vt = (_Float16*)(ws + (size_t)30 * 1024 * 1024);

    cvt_x_kernel<<<(Bc * Sc * HIDc) / (256 * 8), 256, 0, stream>>>(x, xh);
    cvt_w_kernel<<<dim3(HIDc / 64, HIDc / 64, 3), 256, 0, stream>>>(Wq, Wk, Wv, Wt);
    proj_kernel<<<dim3(HIDc / 128, (Bc * Sc) / 128, 3), 256, 0, stream>>>(
        xh, Wt, bq, bk, bv, qw, kw, vt);
    attn_kernel<<<dim3(Sc / 128, Bc * Hc), 256, 0, stream>>>(qw, kw, vt, mask, out);
}